// Round 7
// baseline (6139.249 us; speedup 1.0000x reference)
//
#include <hip/hip_runtime.h>
#include <hip/hip_bf16.h>

#define NSN 5000
#define NMN 100000
#define NRN 2000
#define HDIM 128
#define ESM 2000000
#define ERM 1000000
#define ESIM 2000000
#define LBL 500000

#define CNT_TOTAL (4 * NMN + NSN + NRN)  // 407000
#define POOL_TOTAL (2 * ESM + 2 * ERM + 2 * ESIM)  // 10M
#define NBTOT 1221
#define WCAP 14336   // LDS window capacity (ints) = 56 KB
#define SR_TOTAL (NSN + NRN)  // 7000

// sr region sort: payload (m-id) >> 11 -> 49 regions of 512KB
#define NREG_SR 49
#define NKEY 784  // 16 * 49 (sr composite); also >= 512 generic, >= 200+512 si use

// si merged C+D: 391 buckets of 256 targets; groups of 32 nodes (8/bucket)
// region = src >> 12 -> 25 regions of 1MB
#define NREG_SI 25
#define NSIB 391
#define NGRP 3125  // 100000/32

// padded staging: family caps (ints per bucket), bases in int units
#define CAP0 12288  // sm-fwd, 196 buckets (mean 10204)
#define CAP1 8192   // sm-rev, 313 buckets (mean 6390)
#define CAP2 7168   // rm-fwd, 196 buckets (mean 5102)
#define CAP3 9216   // rm-rev, 125 buckets (mean 8000)
#define CAP4 12288  // si merged C+D, 391 buckets (mean 10240, +20 sigma)
#define PB0 0
#define PB1 (PB0 + 196 * CAP0)  // 2408448
#define PB2 (PB1 + 313 * CAP1)  // 4972544
#define PB3 (PB2 + 196 * CAP2)  // 6377472
#define PB4 (PB3 + 125 * CAP3)  // 7529472
#define STAGE_TOTAL (PB4 + NSIB * CAP4)  // 12334080 ints = 49.3 MB (aliases aggA/aggB)

typedef short bf16x8 __attribute__((ext_vector_type(8)));
typedef float f32x4 __attribute__((ext_vector_type(4)));
typedef float f32x2 __attribute__((ext_vector_type(2)));

__device__ __forceinline__ unsigned short f2bf(float f) {
  unsigned u = __float_as_uint(f);
  unsigned r = (u + 0x7fffu + ((u >> 16) & 1u)) >> 16;  // RNE
  return (unsigned short)r;
}
__device__ __forceinline__ float bf_lo(unsigned v) { return __uint_as_float(v << 16); }
__device__ __forceinline__ float bf_hi(unsigned v) { return __uint_as_float(v & 0xffff0000u); }
__device__ __forceinline__ unsigned pack2(float x, float y) {
  return (unsigned)f2bf(x) | ((unsigned)f2bf(y) << 16);
}
__device__ __forceinline__ void unpack8(uint4 v, float* f) {
  f[0] = bf_lo(v.x); f[1] = bf_hi(v.x);
  f[2] = bf_lo(v.y); f[3] = bf_hi(v.y);
  f[4] = bf_lo(v.z); f[5] = bf_hi(v.z);
  f[6] = bf_lo(v.w); f[7] = bf_hi(v.w);
}
__device__ __forceinline__ float rl_f(float v, int lane) {
  return __uint_as_float((unsigned)__builtin_amdgcn_readlane((int)__float_as_uint(v), lane));
}

// ---------------- CSR build ----------------

// Bucket table: id -> (node-slot group base g, node range [ns,ne))
// sm fwd: 0..195 (NM,>>9)  sm rev: 196..508 (NS,>>4)
// rm fwd: 509..704         rm rev: 705..829 (NR,>>4)
// si merged: 830..1220 (NM,>>8)
struct BInfo { int g; int ns; int ne; };
__device__ __forceinline__ BInfo binfo(int id) {
  BInfo bi;
  if (id < 196)       { int k = id;        bi.g = 0;                   bi.ns = k << 9; bi.ne = min(bi.ns + 512, NMN); }
  else if (id < 509)  { int k = id - 196;  bi.g = NMN;                 bi.ns = k << 4; bi.ne = min(bi.ns + 16,  NSN); }
  else if (id < 705)  { int k = id - 509;  bi.g = NMN + NSN;           bi.ns = k << 9; bi.ne = min(bi.ns + 512, NMN); }
  else if (id < 830)  { int k = id - 705;  bi.g = 2 * NMN + NSN;       bi.ns = k << 4; bi.ne = min(bi.ns + 16,  NRN); }
  else                { int k = id - 830;  bi.g = -1;                  bi.ns = k << 8; bi.ne = min(bi.ns + 256, NMN); }
  return bi;
}

__device__ __forceinline__ int pstart(int id) {
  if (id < 196)       return PB0 + id * CAP0;
  else if (id < 509)  return PB1 + (id - 196) * CAP1;
  else if (id < 705)  return PB2 + (id - 509) * CAP2;
  else if (id < 830)  return PB3 + (id - 705) * CAP3;
  else                return PB4 + (id - 830) * CAP4;
}

// init bucket cursors + zero fallback node cursors (one launch)
__global__ void init_all(int* __restrict__ bcur, int* __restrict__ cnt) {
  int i = blockIdx.x * blockDim.x + threadIdx.x;
  if (i < NBTOT) bcur[i] = pstart(i);
  if (i < CNT_TOTAL) cnt[i] = 0;
}

// Phase A: multisplit edges into padded bucket staging.
// Entry packed: (local_target << 17) | payload  (sm/rm families)
template <int SHF, int NBF, int SHR, int NBR_>
__global__ __launch_bounds__(256) void multisplit(
    const int* __restrict__ a, const int* __restrict__ b, int n,
    int* __restrict__ bcur, int bb, int* __restrict__ stage) {
  __shared__ int hist[NBF + NBR_];
  __shared__ int gpos[NBF + NBR_];
  int tid = threadIdx.x;
  int base = blockIdx.x * 4096;
  for (int k = tid; k < NBF + NBR_; k += 256) hist[k] = 0;
  __syncthreads();
  int dv[16], sv[16];
#pragma unroll
  for (int j = 0; j < 16; j++) {
    int idx = base + j * 256 + tid;
    if (idx < n) {
      sv[j] = a[idx]; dv[j] = b[idx];
      atomicAdd(&hist[dv[j] >> SHF], 1);
      atomicAdd(&hist[NBF + (sv[j] >> SHR)], 1);
    } else {
      dv[j] = -1;
    }
  }
  __syncthreads();
  for (int k = tid; k < NBF + NBR_; k += 256) {
    int c = hist[k];
    gpos[k] = c ? atomicAdd(&bcur[bb + k], c) : 0;
  }
  __syncthreads();
#pragma unroll
  for (int j = 0; j < 16; j++) {
    if (dv[j] >= 0) {
      int s1 = atomicAdd(&gpos[dv[j] >> SHF], 1);
      stage[s1] = ((dv[j] & ((1 << SHF) - 1)) << 17) | sv[j];
      int s2 = atomicAdd(&gpos[NBF + (sv[j] >> SHR)], 1);
      stage[s2] = ((sv[j] & ((1 << SHR) - 1)) << 17) | dv[j];
    }
  }
}

// si multisplit: both directions into ONE family (391 buckets by target>>8).
// Stage entry: (tloc[8b] << 18) | (dir[1b] << 17) | src[17b]
__global__ __launch_bounds__(256) void multisplit_si(
    const int* __restrict__ a, const int* __restrict__ b, int n,
    int* __restrict__ bcur, int* __restrict__ stage) {
  __shared__ int hist[NSIB];
  __shared__ int gpos[NSIB];
  int tid = threadIdx.x;
  int base = blockIdx.x * 4096;
  for (int k = tid; k < NSIB; k += 256) hist[k] = 0;
  __syncthreads();
  int dv[16], sv[16];
#pragma unroll
  for (int j = 0; j < 16; j++) {
    int idx = base + j * 256 + tid;
    if (idx < n) {
      sv[j] = a[idx]; dv[j] = b[idx];           // edge u=sv -> v=dv
      atomicAdd(&hist[dv[j] >> 8], 1);          // C entry at target v
      atomicAdd(&hist[sv[j] >> 8], 1);          // D entry at target u
    } else {
      dv[j] = -1;
    }
  }
  __syncthreads();
  for (int k = tid; k < NSIB; k += 256) {
    int c = hist[k];
    gpos[k] = c ? atomicAdd(&bcur[830 + k], c) : 0;
  }
  __syncthreads();
#pragma unroll
  for (int j = 0; j < 16; j++) {
    if (dv[j] >= 0) {
      int s1 = atomicAdd(&gpos[dv[j] >> 8], 1);
      stage[s1] = ((dv[j] & 255) << 18) | (0 << 17) | sv[j];
      int s2 = atomicAdd(&gpos[sv[j] >> 8], 1);
      stage[s2] = ((sv[j] & 255) << 18) | (1 << 17) | dv[j];
    }
  }
}

__global__ void scan_counts(const int* __restrict__ bcur, int* __restrict__ bstart,
                            int* __restrict__ off_sentinel) {
  __shared__ int buf[256];
  int t = threadIdx.x;
  int base = 0;
  for (int c0 = 0; c0 < NBTOT; c0 += 256) {
    int id = c0 + t;
    int v = (id < NBTOT) ? (bcur[id] - pstart(id)) : 0;
    buf[t] = v; __syncthreads();
    for (int o = 1; o < 256; o <<= 1) {
      int a = (t >= o) ? buf[t - o] : 0;
      __syncthreads();
      buf[t] += a;
      __syncthreads();
    }
    if (id < NBTOT) bstart[id] = buf[t] - v + base;
    base += buf[255];
    __syncthreads();
  }
  if (t == 0) { bstart[NBTOT] = base; *off_sentinel = base; }
}

// Phase B: one block per bucket.
// - sr buckets: composite (target x 512KB-region) sort.
// - si buckets: sort by (group-of-32, 1MB-region); pool entry tagged
//   (tag[6b]=(nd<<1)|dir)<<17 | src; writes wstart, dinv1/dinv2 directly.
// - others: plain per-target counting sort.
__global__ __launch_bounds__(256) void scatter_bucket(
    const int* __restrict__ stage, const int* __restrict__ bstart,
    int* __restrict__ cur, int* __restrict__ off, int* __restrict__ pool,
    int* __restrict__ wstart, float* __restrict__ dinv1, float* __restrict__ dinv2) {
  __shared__ int win[WCAP];
  __shared__ int hist[NKEY];
  __shared__ int part[256];
  int b = blockIdx.x;
  BInfo bi = binfo(b);
  int p0 = pstart(b);
  int d0 = bstart[b];
  int sz = bstart[b + 1] - d0;
  int nn = bi.ne - bi.ns;
  int t = threadIdx.x;

  if (b >= 830) {
    // ---- si merged bucket: 256 targets, 8 groups of 32 ----
    int* keyh = hist;              // [0..199]   (8 groups x 25 regions)
    int* degC = hist + 200;        // [200..455]
    int* degD = hist + 456;        // [456..711]
    for (int k = t; k < 712; k += 256) hist[k] = 0;
    __syncthreads();
    for (int k = t; k < sz; k += 256) {
      unsigned e = (unsigned)stage[p0 + k];
      int tloc = e >> 18, dir = (e >> 17) & 1, src = e & 0x1FFFF;
      atomicAdd(&keyh[(tloc >> 5) * NREG_SI + (src >> 12)], 1);
      atomicAdd(dir ? &degD[tloc] : &degC[tloc], 1);
    }
    __syncthreads();
    int c = (t < 200) ? keyh[t] : 0;
    part[t] = c;
    __syncthreads();
    for (int o = 1; o < 256; o <<= 1) {
      int a = (t >= o) ? part[t - o] : 0;
      __syncthreads();
      part[t] += a;
      __syncthreads();
    }
    if (t < 200) keyh[t] = part[t] - c;  // exclusive
    __syncthreads();
    int ngl = (nn + 31) >> 5;
    if (t < ngl) wstart[(b - 830) * 8 + t] = d0 + keyh[t * NREG_SI];
    if (b == 1220 && t == 0) wstart[NGRP] = bstart[NBTOT];
    if (b == 830 && t == 0) off[2 * NMN + NSN + NRN] = d0;  // off_mr sentinel
    if (t < nn) {
      int node = bi.ns + t;
      dinv1[node] = rsqrtf((float)(degC[t] + 1));
      dinv2[node] = rsqrtf((float)(degD[t] + 1));
    }
    __syncthreads();
    for (int k = t; k < sz; k += 256) {
      unsigned e = (unsigned)stage[p0 + k];
      int tloc = e >> 18, dir = (e >> 17) & 1, src = e & 0x1FFFF;
      int slot = atomicAdd(&keyh[(tloc >> 5) * NREG_SI + (src >> 12)], 1);
      win[slot] = ((((tloc & 31) << 1) | dir) << 17) | src;
    }
    __syncthreads();
    for (int k = t; k < sz; k += 256) pool[d0 + k] = win[k];
    return;
  }

  bool srb = (b >= 196 && b < 509) || (b >= 705 && b < 830);
  if (srb) {
    for (int k = t; k < NKEY; k += 256) hist[k] = 0;
    __syncthreads();
    for (int k = t; k < sz; k += 256) {
      unsigned e = (unsigned)stage[p0 + k];
      atomicAdd(&hist[(e >> 17) * NREG_SR + ((e & 0x1FFFF) >> 11)], 1);
    }
    __syncthreads();
    int c4[4]; int sum4 = 0;
#pragma unroll
    for (int i = 0; i < 4; i++) {
      int idx = 4 * t + i;
      c4[i] = (idx < NKEY) ? hist[idx] : 0;
      sum4 += c4[i];
    }
    part[t] = sum4;
    __syncthreads();
    for (int o = 1; o < 256; o <<= 1) {
      int a = (t >= o) ? part[t - o] : 0;
      __syncthreads();
      part[t] += a;
      __syncthreads();
    }
    int run = part[t] - sum4;
#pragma unroll
    for (int i = 0; i < 4; i++) {
      int idx = 4 * t + i;
      if (idx < NKEY) { hist[idx] = run; run += c4[i]; }
    }
    __syncthreads();
    if (t < nn) off[bi.g + bi.ns + t] = d0 + hist[t * NREG_SR];
    __syncthreads();
    for (int k = t; k < sz; k += 256) {
      unsigned e = (unsigned)stage[p0 + k];
      int slot = atomicAdd(&hist[(e >> 17) * NREG_SR + ((e & 0x1FFFF) >> 11)], 1);
      win[slot] = e & 0x1FFFF;
    }
    __syncthreads();
    for (int k = t; k < sz; k += 256) pool[d0 + k] = win[k];
    return;
  }

  for (int k = t; k < nn; k += 256) hist[k] = 0;
  __syncthreads();
  for (int k = t; k < sz; k += 256)
    atomicAdd(&hist[((unsigned)stage[p0 + k]) >> 17], 1);
  __syncthreads();
  int a0 = (2 * t < nn) ? hist[2 * t] : 0;
  int a1 = (2 * t + 1 < nn) ? hist[2 * t + 1] : 0;
  part[t] = a0 + a1;
  __syncthreads();
  for (int o = 1; o < 256; o <<= 1) {
    int a = (t >= o) ? part[t - o] : 0;
    __syncthreads();
    part[t] += a;
    __syncthreads();
  }
  int e0 = part[t] - a0 - a1;
  int e1 = e0 + a0;
  if (2 * t < nn)     { off[bi.g + bi.ns + 2 * t] = d0 + e0; hist[2 * t] = e0; }
  if (2 * t + 1 < nn) { off[bi.g + bi.ns + 2 * t + 1] = d0 + e1; hist[2 * t + 1] = e1; }
  __syncthreads();
  if (sz <= WCAP) {
    for (int k = t; k < sz; k += 256) {
      int e = stage[p0 + k];
      int slot = atomicAdd(&hist[((unsigned)e) >> 17], 1);
      win[slot] = e & 0x1FFFF;
    }
    __syncthreads();
    for (int k = t; k < sz; k += 256) pool[d0 + k] = win[k];
  } else {
    for (int k = t; k < sz; k += 256) {
      int e = stage[p0 + k];
      int local = ((unsigned)e) >> 17;
      int slot = atomicAdd(&cur[bi.g + bi.ns + local], 1);
      pool[d0 + hist[local] + slot] = e & 0x1FFFF;
    }
  }
}

// merged prep: weight transpose+cast + fused bias
__global__ void prep_all(const float* __restrict__ sWl, const float* __restrict__ sWr,
                         const float* __restrict__ gW, const float* __restrict__ sbl,
                         const float* __restrict__ gb,
                         unsigned short* __restrict__ wt, float* __restrict__ biasM) {
  int i = blockIdx.x * blockDim.x + threadIdx.x;
  if (i < 18 * 16384) {
    int mat = i >> 14, l = mat / 9, slot = mat % 9;
    int idx = i & 16383, nn = idx >> 7, kk = idx & 127;
    int s_ = kk * 128 + nn;  // source [k][n] row-major
    float v;
    if (slot < 4)      v = sWl[((l * 4 + slot) << 14) + s_];
    else if (slot < 6) v = gW[((l * 2 + (slot - 4)) << 14) + s_];
    else if (slot == 6) v = sWr[((l * 4 + 0) << 14) + s_] + sWr[((l * 4 + 2) << 14) + s_];
    else if (slot == 7) v = sWr[((l * 4 + 1) << 14) + s_];
    else                v = sWr[((l * 4 + 3) << 14) + s_];
    wt[i] = f2bf(v);
  }
  if (i < 256) {
    int l = i >> 7, j = i & 127;
    biasM[i] = sbl[(l * 4 + 0) * 128 + j] + sbl[(l * 4 + 2) * 128 + j] +
               gb[(l * 2 + 0) * 128 + j] + gb[(l * 2 + 1) * 128 + j];
  }
}

__global__ void cast_all(const float2* __restrict__ es, const float2* __restrict__ em,
                         const float2* __restrict__ er, unsigned* __restrict__ os,
                         unsigned* __restrict__ om, unsigned* __restrict__ orr) {
  int i = blockIdx.x * blockDim.x + threadIdx.x;
  if (i < NSN * 64) { float2 v = es[i]; os[i] = pack2(v.x, v.y); }
  if (i < NMN * 64) { float2 v = em[i]; om[i] = pack2(v.x, v.y); }
  if (i < NRN * 64) { float2 v = er[i]; orr[i] = pack2(v.x, v.y); }
}

// ---------------- si aggregation: region-synced cohort, LDS accumulators ----
// One BLOCK (4 waves) per group of 32 m-nodes; merged C+D list sorted by 1MB
// source region; waves take interleaved 64-entry chunks (same region window).
// Accumulators in LDS acc[64 slots][64 lanes][2] (32 KB) updated with
// ds_add_f32 atomics -- dynamic slot indexing is native in LDS (R6's VGPR
// switch was lowered to 130 predicated VALU ops/edge; this is ~10 + 2 DS).
// Bank layout: lane l -> byte l*8 -> 2-way alias = free (m136).

__global__ __launch_bounds__(256) void agg_si(
    const unsigned* __restrict__ xm, const int* __restrict__ pool,
    const int* __restrict__ wstart,
    const float* __restrict__ dinv1, const float* __restrict__ dinv2,
    unsigned* __restrict__ aggC, unsigned* __restrict__ aggD) {
  __shared__ float acc[64 * 64 * 2];  // [slot][lane][lo/hi] = 32 KB
  int g = blockIdx.x;
  int tid = threadIdx.x;
  int w = tid >> 6, l = tid & 63;
  int l4 = l << 2;
  const char* xb = (const char*)xm;

  for (int i = tid; i < 64 * 64 * 2; i += 256) acc[i] = 0.f;
  __syncthreads();

  int s = wstart[g], e = wstart[g + 1];
  for (int c0 = s + w * 64; c0 < e; c0 += 256) {
    int cnt = min(64, e - c0);
    int pv = pool[min(c0 + l, e - 1)];  // (tag6<<17)|src17, coalesced
    const float* dp = (pv & 0x20000) ? dinv2 : dinv1;
    float dvv = dp[pv & 0x1FFFF];
    for (int k = 0; k < cnt; k += 8) {
      unsigned vv[8]; float sc[8]; int tg[8];
#pragma unroll
      for (int j = 0; j < 8; j++) {
        int kk = min(k + j, cnt - 1);
        int rl = __builtin_amdgcn_readlane(pv, kk);   // SGPR entry
        sc[j] = (k + j < cnt) ? rl_f(dvv, kk) : 0.f;
        tg[j] = ((unsigned)rl) >> 17;
        vv[j] = *(const unsigned*)(xb + (((unsigned)(rl & 0x1FFFF)) << 8) + (unsigned)l4);
      }
#pragma unroll
      for (int j = 0; j < 8; j++) {
        float lo = bf_lo(vv[j]) * sc[j];
        float hi = bf_hi(vv[j]) * sc[j];
        atomicAdd(&acc[(tg[j] << 7) + (l << 1)], lo);
        atomicAdd(&acc[(tg[j] << 7) + (l << 1) + 1], hi);
      }
    }
  }
  __syncthreads();

  int n0 = g * 32;  // 3125*32 == 100000 exactly
#pragma unroll
  for (int i = 0; i < 8; i++) {
    int nd = w * 8 + i;
    int node = n0 + nd;
    float d1 = dinv1[node], d2 = dinv2[node];
    unsigned xv = xm[(size_t)node * 64 + l];
    float xlo = bf_lo(xv), xhi = bf_hi(xv);
    float aCl = acc[((nd * 2) << 7) + (l << 1)];
    float aCh = acc[((nd * 2) << 7) + (l << 1) + 1];
    float aDl = acc[((nd * 2 + 1) << 7) + (l << 1)];
    float aDh = acc[((nd * 2 + 1) << 7) + (l << 1) + 1];
    float cx = aCl * d1 + xlo * d1 * d1;
    float cy = aCh * d1 + xhi * d1 * d1;
    float dx = aDl * d2 + xlo * d2 * d2;
    float dy = aDh * d2 + xhi * d2 * d2;
    aggC[(size_t)node * 64 + l] = pack2(cx, cy);
    aggD[(size_t)node * 64 + l] = pack2(dx, dy);
  }
}

// ---------------- sr + m A/B aggregation (1 wave per node) -------------------

template <bool GCN>
__device__ __forceinline__ f32x2 agg_list(const char* __restrict__ xb,
                                          const int* __restrict__ pool,
                                          const float* __restrict__ dinv,
                                          int s, int e, int l4) {
  f32x2 a0 = (f32x2)(0.f), a1 = (f32x2)(0.f);
  if (e <= s) return a0;
  for (int i0 = s; i0 < e; i0 += 64) {
    int cnt = min(64, e - i0);
    int pidx = min(i0 + (l4 >> 2), e - 1);
    int pv = pool[pidx];
    float dvv = 0.f;
    if (GCN) dvv = dinv[pv];
    int k = 0;
    for (; k + 16 <= cnt; k += 16) {
      unsigned vv[16];
      float sc[16];
#pragma unroll
      for (int j = 0; j < 16; j++) {
        int u = __builtin_amdgcn_readlane(pv, k + j);
        if (GCN) sc[j] = rl_f(dvv, k + j);
        vv[j] = *(const unsigned*)(xb + (((unsigned)u << 8) + (unsigned)l4));
      }
#pragma unroll
      for (int j = 0; j < 16; j++) {
        float m = GCN ? sc[j] : 1.0f;
        if (j & 1) {
          a1.x = fmaf(bf_lo(vv[j]), m, a1.x);
          a1.y = fmaf(bf_hi(vv[j]), m, a1.y);
        } else {
          a0.x = fmaf(bf_lo(vv[j]), m, a0.x);
          a0.y = fmaf(bf_hi(vv[j]), m, a0.y);
        }
      }
    }
    if (k < cnt) {
      unsigned vv[16];
      float sc[16];
#pragma unroll
      for (int j = 0; j < 16; j++) {
        int kk = min(k + j, cnt - 1);
        int u = __builtin_amdgcn_readlane(pv, kk);
        float m;
        if (k + j < cnt)
          m = GCN ? rl_f(dvv, kk) : 1.0f;
        else
          m = 0.0f;
        sc[j] = m;
        vv[j] = *(const unsigned*)(xb + (((unsigned)u << 8) + (unsigned)l4));
      }
#pragma unroll
      for (int j = 0; j < 16; j++) {
        if (j & 1) {
          a1.x = fmaf(bf_lo(vv[j]), sc[j], a1.x);
          a1.y = fmaf(bf_hi(vv[j]), sc[j], a1.y);
        } else {
          a0.x = fmaf(bf_lo(vv[j]), sc[j], a0.x);
          a0.y = fmaf(bf_hi(vv[j]), sc[j], a0.y);
        }
      }
    }
  }
  return a0 + a1;
}

__global__ __launch_bounds__(256) void agg_main(
    const unsigned* __restrict__ xs, const unsigned* __restrict__ xm,
    const unsigned* __restrict__ xr, const int* __restrict__ pool,
    const int* __restrict__ off_sm, const int* __restrict__ off_rm,
    const int* __restrict__ off_ms, const int* __restrict__ off_mr,
    unsigned* __restrict__ aggA, unsigned* __restrict__ aggB,
    unsigned* __restrict__ aggS, unsigned* __restrict__ aggR) {
  int wv = blockIdx.x * 4 + (threadIdx.x >> 6);
  wv = __builtin_amdgcn_readfirstlane(wv);
  int l = threadIdx.x & 63;
  int l4 = l << 2;

  if (wv < SR_TOTAL) {
    int node;
    const int* offp;
    unsigned* outb;
    if (wv < NSN) { node = wv; offp = off_ms; outb = aggS; }
    else          { node = wv - NSN; offp = off_mr; outb = aggR; }
    int s = offp[node], e = offp[node + 1];
    f32x2 a = agg_list<false>((const char*)xm, pool, nullptr, s, e, l4);
    float inv = (e > s) ? 1.0f / (float)(e - s) : 0.0f;
    outb[(size_t)node * 64 + l] = pack2(a.x * inv, a.y * inv);
  } else {
    int w = wv - SR_TOTAL;
    int sA = off_sm[w], eA = off_sm[w + 1];
    int sB = off_rm[w], eB = off_rm[w + 1];
    {
      f32x2 a = agg_list<false>((const char*)xs, pool, nullptr, sA, eA, l4);
      float inv = (eA > sA) ? 1.0f / (float)(eA - sA) : 0.0f;
      aggA[(size_t)w * 64 + l] = pack2(a.x * inv, a.y * inv);
    }
    {
      f32x2 a = agg_list<false>((const char*)xr, pool, nullptr, sB, eB, l4);
      float inv = (eB > sB) ? 1.0f / (float)(eB - sB) : 0.0f;
      aggB[(size_t)w * 64 + l] = pack2(a.x * inv, a.y * inv);
    }
  }
}

// ---------------- MFMA GEMM: out = relu(bias + sum_p A_p @ W_p) ----------------

#define LDA 136
#define NBS 79    // ceil(5000/64)
#define NBR 32    // ceil(2000/64)
#define NBM 1563  // ceil(100000/64)
#define NB_GEMM (NBM + NBS + NBR)  // 1674

__global__ __launch_bounds__(256) void gemm_all(
    const unsigned short* __restrict__ aggA, const unsigned short* __restrict__ aggB,
    const unsigned short* __restrict__ aggC, const unsigned short* __restrict__ aggD,
    const unsigned short* __restrict__ xm_c, const unsigned short* __restrict__ aggS,
    const unsigned short* __restrict__ xs_c, const unsigned short* __restrict__ aggR,
    const unsigned short* __restrict__ xr_c,
    const unsigned short* __restrict__ wt, int layer,
    const float* __restrict__ biasM, const float* __restrict__ sbl,
    unsigned short* __restrict__ xm_n, unsigned short* __restrict__ xs_n,
    unsigned short* __restrict__ xr_n) {
  __shared__ __align__(16) unsigned short As[64 * LDA];
  __shared__ __align__(16) unsigned short Ws[128 * LDA];

  int b = blockIdx.x, tid = threadIdx.x;
  int w = tid >> 6, lane = tid & 63;
  int q = lane >> 4, c = lane & 15;

  const unsigned short* wbase = wt + (((size_t)layer * 9) << 14);
  const unsigned short* Ap[5];
  const unsigned short* Wp[5];
  int base, n;
  unsigned short* outp;
  const float* bias;

  if (b < NBM) {
    base = b * 64; n = NMN; outp = xm_n; bias = biasM + layer * 128;
    Ap[0] = aggA; Wp[0] = wbase + (0 << 14);
    Ap[1] = aggB; Wp[1] = wbase + (2 << 14);
    Ap[2] = aggC; Wp[2] = wbase + (4 << 14);
    Ap[3] = aggD; Wp[3] = wbase + (5 << 14);
    Ap[4] = xm_c; Wp[4] = wbase + (6 << 14);
  } else if (b < NBM + NBS) {
    base = (b - NBM) * 64; n = NSN; outp = xs_n; bias = sbl + (layer * 4 + 1) * 128;
    Ap[0] = aggS; Wp[0] = wbase + (1 << 14);
    Ap[1] = xs_c; Wp[1] = wbase + (7 << 14);
    Ap[2] = nullptr; Ap[3] = nullptr; Ap[4] = nullptr;
    Wp[2] = nullptr; Wp[3] = nullptr; Wp[4] = nullptr;
  } else {
    base = (b - NBM - NBS) * 64; n = NRN; outp = xr_n; bias = sbl + (layer * 4 + 3) * 128;
    Ap[0] = aggR; Wp[0] = wbase + (3 << 14);
    Ap[1] = xr_c; Wp[1] = wbase + (8 << 14);
    Ap[2] = nullptr; Ap[3] = nullptr; Ap[4] = nullptr;
    Wp[2] = nullptr; Wp[3] = nullptr; Wp[4] = nullptr;
  }

  float bias_v[8];
#pragma unroll
  for (int n0 = 0; n0 < 8; n0++) bias_v[n0] = bias[n0 * 16 + c];

  f32x4 acc[8];
#pragma unroll
  for (int n0 = 0; n0 < 8; n0++) acc[n0] = (f32x4){0.f, 0.f, 0.f, 0.f};

  for (int p = 0; p < 5; p++) {
    if (!Ap[p]) continue;
    __syncthreads();
    for (int j = tid; j < 2048; j += 256) {
      int row = j >> 4, colc = (j & 15) * 8;
      *(uint4*)&Ws[row * LDA + colc] = *(const uint4*)(Wp[p] + row * 128 + colc);
    }
    for (int j = tid; j < 1024; j += 256) {
      int row = j >> 4, colc = (j & 15) * 8;
      uint4 v = make_uint4(0u, 0u, 0u, 0u);
      if (base + row < n) v = *(const uint4*)(Ap[p] + (size_t)(base + row) * 128 + colc);
      *(uint4*)&As[row * LDA + colc] = v;
    }
    __syncthreads();

    int arow = (w * 16 + c) * LDA;
#pragma unroll
    for (int k0 = 0; k0 < 128; k0 += 32) {
      bf16x8 af = *(const bf16x8*)&As[arow + k0 + q * 8];
#pragma unroll
      for (int n0 = 0; n0 < 8; n0++) {
        bf16x8 bfv = *(const bf16x8*)&Ws[(n0 * 16 + c) * LDA + k0 + q * 8];
        acc[n0] = __builtin_amdgcn_mfma_f32_16x16x32_bf16(af, bfv, acc[n0], 0, 0, 0);
      }
    }
  }

  __syncthreads();
#pragma unroll
  for (int n0 = 0; n0 < 8; n0++) {
#pragma unroll
    for (int reg = 0; reg < 4; reg++) {
      float v = acc[n0][reg] + bias_v[n0];
      v = fmaxf(v, 0.f);
      As[(w * 16 + q * 4 + reg) * LDA + n0 * 16 + c] = f2bf(v);
    }
  }
  __syncthreads();
  for (int j = tid; j < 1024; j += 256) {
    int row = j >> 4, colc = (j & 15) * 8;
    if (base + row < n)
      *(uint4*)(outp + (size_t)(base + row) * 128 + colc) = *(const uint4*)&As[row * LDA + colc];
  }
}

// ---------------- final dot products (4 pairs per wave) ----------------

__global__ void dots_kernel(const unsigned* __restrict__ xs, const unsigned* __restrict__ xm,
                            const unsigned* __restrict__ xr, const int* __restrict__ ls,
                            const int* __restrict__ lm, const int* __restrict__ lr,
                            float* __restrict__ out) {
  int wv = (blockIdx.x * blockDim.x + threadIdx.x) >> 6;
  int lane = threadIdx.x & 63;
  int q = lane >> 4, h = lane & 15;
  int i = wv * 4 + q;
  if (i >= LBL) return;
  int im = lm[i], is = ls[i], ir = lr[i];
  uint4 mv = *(const uint4*)(xm + (size_t)im * 64 + h * 4);
  uint4 sv = *(const uint4*)(xs + (size_t)is * 64 + h * 4);
  uint4 rv = *(const uint4*)(xr + (size_t)ir * 64 + h * 4);
  float fm[8], fs[8], fr[8];
  unpack8(mv, fm); unpack8(sv, fs); unpack8(rv, fr);
  float p1 = 0.f, p2 = 0.f;
#pragma unroll
  for (int j = 0; j < 8; j++) { p1 = fmaf(fs[j], fm[j], p1); p2 = fmaf(fr[j], fm[j], p2); }
#pragma unroll
  for (int m = 1; m < 16; m <<= 1) {
    p1 += __shfl_xor(p1, m, 64);
    p2 += __shfl_xor(p2, m, 64);
  }
  if (h == 0) { out[i] = p1; out[LBL + i] = p2; }
}

// ---------------- host launcher ----------------

extern "C" void kernel_launch(void* const* d_in, const int* in_sizes, int n_in,
                              void* d_out, int out_size, void* d_ws, size_t ws_size,
                              hipStream_t stream) {
  const float* emb_s = (const float*)d_in[0];
  const float* emb_m = (const float*)d_in[1];
  const float* emb_r = (const float*)d_in[2];
  const float* sWl = (const float*)d_in[3];
  const float* sbl = (const float*)d_in[4];
  const float* sWr = (const float*)d_in[5];
  const float* gW  = (const float*)d_in[6];
  const float* gb  = (const float*)d_in[7];
  const int* src_sm  = (const int*)d_in[8];
  const int* dst_sm  = (const int*)d_in[9];
  const int* src_rm  = (const int*)d_in[10];
  const int* dst_rm  = (const int*)d_in[11];
  const int* src_sim = (const int*)d_in[12];
  const int* dst_sim = (const int*)d_in[13];
  const int* lbl_s = (const int*)d_in[14];
  const int* lbl_m = (const int*)d_in[15];
  const int* lbl_r = (const int*)d_in[16];
  float* out = (float*)d_out;

  char* p = (char*)d_ws;
  auto alloc = [&](size_t bytes) -> char* {
    char* r = p;
    p += (bytes + 255) & ~(size_t)255;
    return r;
  };

  int* cnt_base = (int*)alloc(sizeof(int) * CNT_TOTAL);  // fallback cursors only

  int* off_base = (int*)alloc(sizeof(int) * (CNT_TOTAL + 1));
  int* off_sm  = off_base;
  int* off_ms  = off_sm + NMN;
  int* off_rm  = off_ms + NSN;
  int* off_mr  = off_rm + NMN;

  int* bstart = (int*)alloc(sizeof(int) * 1280);
  int* bcur   = (int*)alloc(sizeof(int) * 1280);
  int* wstart = (int*)alloc(sizeof(int) * (NGRP + 1));
  int* pool = (int*)alloc(sizeof(int) * POOL_TOTAL);

  float* dinv1 = (float*)alloc(sizeof(float) * NMN);
  float* dinv2 = (float*)alloc(sizeof(float) * NMN);

  unsigned* xsb = (unsigned*)alloc(sizeof(unsigned) * (size_t)NSN * 64);
  unsigned* xmb = (unsigned*)alloc(sizeof(unsigned) * (size_t)NMN * 64);
  unsigned* xrb = (unsigned*)alloc(sizeof(unsigned) * (size_t)NRN * 64);
  unsigned* xs0 = (unsigned*)alloc(sizeof(unsigned) * (size_t)NSN * 64);
  unsigned* xs1 = (unsigned*)alloc(sizeof(unsigned) * (size_t)NSN * 64);
  unsigned* xm0 = (unsigned*)alloc(sizeof(unsigned) * (size_t)NMN * 64);
  unsigned* xm1 = (unsigned*)alloc(sizeof(unsigned) * (size_t)NMN * 64);
  unsigned* xr0 = (unsigned*)alloc(sizeof(unsigned) * (size_t)NRN * 64);
  unsigned* xr1 = (unsigned*)alloc(sizeof(unsigned) * (size_t)NRN * 64);
  unsigned* aggA = (unsigned*)alloc(sizeof(unsigned) * (size_t)NMN * 64);
  unsigned* aggB = (unsigned*)alloc(sizeof(unsigned) * (size_t)NMN * 64);
  unsigned* aggC = (unsigned*)alloc(sizeof(unsigned) * (size_t)NMN * 64);
  unsigned* aggD = (unsigned*)alloc(sizeof(unsigned) * (size_t)NMN * 64);
  unsigned* aggS = (unsigned*)alloc(sizeof(unsigned) * (size_t)NSN * 64);
  unsigned* aggR = (unsigned*)alloc(sizeof(unsigned) * (size_t)NRN * 64);

  unsigned short* wt = (unsigned short*)alloc(sizeof(unsigned short) * 18 * 16384);
  float* biasM = (float*)alloc(sizeof(float) * 2 * 128);

  // packed staging aliases aggA/aggB (49.3 MB <= 51.2 MB contiguous); staging
  // fully consumed by scatter_bucket before agg writes aggA/aggB.
  int* stage = (int*)aggA;

  // ---- CSR build ----
  init_all<<<(CNT_TOTAL + 255) / 256, 256, 0, stream>>>(bcur, cnt_base);
  multisplit<9, 196, 4, 313><<<(ESM + 4095) / 4096, 256, 0, stream>>>(
      src_sm, dst_sm, ESM, bcur, 0, stage);
  multisplit<9, 196, 4, 125><<<(ERM + 4095) / 4096, 256, 0, stream>>>(
      src_rm, dst_rm, ERM, bcur, 509, stage);
  multisplit_si<<<(ESIM + 4095) / 4096, 256, 0, stream>>>(
      src_sim, dst_sim, ESIM, bcur, stage);
  scan_counts<<<1, 256, 0, stream>>>(bcur, bstart, off_base + CNT_TOTAL);
  scatter_bucket<<<NBTOT, 256, 0, stream>>>(stage, bstart, cnt_base, off_base, pool,
                                            wstart, dinv1, dinv2);

  prep_all<<<(18 * 16384 + 255) / 256, 256, 0, stream>>>(sWl, sWr, gW, sbl, gb, wt, biasM);
  cast_all<<<(NMN * 64 + 255) / 256, 256, 0, stream>>>((const float2*)emb_s, (const float2*)emb_m,
                                                       (const float2*)emb_r, xsb, xmb, xrb);

  const int MAIN_GRID = (SR_TOTAL + NMN) / 4;  // 26750 blocks
  for (int l = 0; l < 2; ++l) {
    const unsigned* xs_c = l ? xs0 : xsb;
    const unsigned* xm_c = l ? xm0 : xmb;
    const unsigned* xr_c = l ? xr0 : xrb;
    unsigned* xs_n = l ? xs1 : xs0;
    unsigned* xm_n = l ? xm1 : xm0;
    unsigned* xr_n = l ? xr1 : xr0;

    agg_si<<<NGRP, 256, 0, stream>>>(xm_c, pool, wstart, dinv1, dinv2, aggC, aggD);
    agg_main<<<MAIN_GRID, 256, 0, stream>>>(
        xs_c, xm_c, xr_c, pool, off_sm, off_rm, off_ms, off_mr,
        aggA, aggB, aggS, aggR);

    gemm_all<<<NB_GEMM, 256, 0, stream>>>(
        (const unsigned short*)aggA, (const unsigned short*)aggB,
        (const unsigned short*)aggC, (const unsigned short*)aggD,
        (const unsigned short*)xm_c, (const unsigned short*)aggS,
        (const unsigned short*)xs_c, (const unsigned short*)aggR,
        (const unsigned short*)xr_c, wt, l, biasM, sbl,
        (unsigned short*)xm_n, (unsigned short*)xs_n, (unsigned short*)xr_n);
  }

  dots_kernel<<<(LBL * 16 + 255) / 256, 256, 0, stream>>>(xs1, xm1, xr1, lbl_s, lbl_m, lbl_r, out);
}

// Round 8
// 1015.954 us; speedup vs baseline: 6.0428x; 6.0428x over previous
//
#include <hip/hip_runtime.h>
#include <hip/hip_bf16.h>

#define NSN 5000
#define NMN 100000
#define NRN 2000
#define HDIM 128
#define ESM 2000000
#define ERM 1000000
#define ESIM 2000000
#define LBL 500000

#define CNT_TOTAL (4 * NMN + NSN + NRN)  // 407000
#define POOL_TOTAL (2 * ESM + 2 * ERM + 2 * ESIM)  // 10M
#define NBTOT 1222
#define WCAP 14336   // LDS window capacity (ints) = 56 KB
#define MAXNODES 512
#define SR_TOTAL (NSN + NRN)  // 7000

// region sort for s/r-target lists: payload (m-id) >> 11 -> 49 regions of 512KB
#define NREG 49
#define NKEY (16 * NREG)  // 784

// padded staging: family caps (ints per bucket), bases in int units
#define CAP0 12288  // sm-fwd, 196 buckets (mean 10204)
#define CAP1 8192   // sm-rev, 313 buckets (mean 6390)
#define CAP2 7168   // rm-fwd, 196 buckets (mean 5102)
#define CAP3 9216   // rm-rev, 125 buckets (mean 8000)
#define CAP4 12288  // si-fwd, 196
#define CAP5 12288  // si-rev, 196
#define PB0 0
#define PB1 (PB0 + 196 * CAP0)  // 2408448
#define PB2 (PB1 + 313 * CAP1)  // 4972544
#define PB3 (PB2 + 196 * CAP2)  // 6377472
#define PB4 (PB3 + 125 * CAP3)  // 7529472
#define PB5 (PB4 + 196 * CAP4)  // 9937920
#define STAGE_TOTAL (PB5 + 196 * CAP5)  // 12346368 ints = 49.4 MB (aliases aggA/aggB)

typedef short bf16x8 __attribute__((ext_vector_type(8)));
typedef float f32x4 __attribute__((ext_vector_type(4)));
typedef float f32x2 __attribute__((ext_vector_type(2)));

__device__ __forceinline__ unsigned short f2bf(float f) {
  unsigned u = __float_as_uint(f);
  unsigned r = (u + 0x7fffu + ((u >> 16) & 1u)) >> 16;  // RNE
  return (unsigned short)r;
}
__device__ __forceinline__ float bf_lo(unsigned v) { return __uint_as_float(v << 16); }
__device__ __forceinline__ float bf_hi(unsigned v) { return __uint_as_float(v & 0xffff0000u); }
__device__ __forceinline__ unsigned pack2(float x, float y) {
  return (unsigned)f2bf(x) | ((unsigned)f2bf(y) << 16);
}
__device__ __forceinline__ void unpack8(uint4 v, float* f) {
  f[0] = bf_lo(v.x); f[1] = bf_hi(v.x);
  f[2] = bf_lo(v.y); f[3] = bf_hi(v.y);
  f[4] = bf_lo(v.z); f[5] = bf_hi(v.z);
  f[6] = bf_lo(v.w); f[7] = bf_hi(v.w);
}
__device__ __forceinline__ float rl_f(float v, int lane) {
  return __uint_as_float((unsigned)__builtin_amdgcn_readlane((int)__float_as_uint(v), lane));
}

// ---------------- CSR build ----------------

// Bucket table: id -> (node-slot group base g, node range [ns,ne))
// sm fwd: 0..195 (NM,>>9)  sm rev: 196..508 (NS,>>4)
// rm fwd: 509..704         rm rev: 705..829 (NR,>>4)
// si fwd: 830..1025        si rev: 1026..1221
struct BInfo { int g; int ns; int ne; };
__device__ __forceinline__ BInfo binfo(int id) {
  BInfo bi;
  if (id < 196)       { int k = id;        bi.g = 0;                   bi.ns = k << 9; bi.ne = min(bi.ns + 512, NMN); }
  else if (id < 509)  { int k = id - 196;  bi.g = NMN;                 bi.ns = k << 4; bi.ne = min(bi.ns + 16,  NSN); }
  else if (id < 705)  { int k = id - 509;  bi.g = NMN + NSN;           bi.ns = k << 9; bi.ne = min(bi.ns + 512, NMN); }
  else if (id < 830)  { int k = id - 705;  bi.g = 2 * NMN + NSN;       bi.ns = k << 4; bi.ne = min(bi.ns + 16,  NRN); }
  else if (id < 1026) { int k = id - 830;  bi.g = 2 * NMN + NSN + NRN; bi.ns = k << 9; bi.ne = min(bi.ns + 512, NMN); }
  else                { int k = id - 1026; bi.g = 3 * NMN + NSN + NRN; bi.ns = k << 9; bi.ne = min(bi.ns + 512, NMN); }
  return bi;
}

__device__ __forceinline__ int pstart(int id) {
  if (id < 196)       return PB0 + id * CAP0;
  else if (id < 509)  return PB1 + (id - 196) * CAP1;
  else if (id < 705)  return PB2 + (id - 509) * CAP2;
  else if (id < 830)  return PB3 + (id - 705) * CAP3;
  else if (id < 1026) return PB4 + (id - 830) * CAP4;
  else                return PB5 + (id - 1026) * CAP5;
}

// init bucket cursors + zero fallback node cursors (one launch)
__global__ void init_all(int* __restrict__ bcur, int* __restrict__ cnt) {
  int i = blockIdx.x * blockDim.x + threadIdx.x;
  if (i < NBTOT) bcur[i] = pstart(i);
  if (i < CNT_TOTAL) cnt[i] = 0;
}

// Phase A: multisplit edges into padded bucket staging.
// Entry packed into one int: (local_target << 17) | payload  (9+17 = 26 bits).
template <int SHF, int NBF, int SHR, int NBR_>
__global__ __launch_bounds__(256) void multisplit(
    const int* __restrict__ a, const int* __restrict__ b, int n,
    int* __restrict__ bcur, int bb, int* __restrict__ stage) {
  __shared__ int hist[NBF + NBR_];
  __shared__ int gpos[NBF + NBR_];
  int tid = threadIdx.x;
  int base = blockIdx.x * 4096;
  for (int k = tid; k < NBF + NBR_; k += 256) hist[k] = 0;
  __syncthreads();
  int dv[16], sv[16];
#pragma unroll
  for (int j = 0; j < 16; j++) {
    int idx = base + j * 256 + tid;
    if (idx < n) {
      sv[j] = a[idx]; dv[j] = b[idx];
      atomicAdd(&hist[dv[j] >> SHF], 1);
      atomicAdd(&hist[NBF + (sv[j] >> SHR)], 1);
    } else {
      dv[j] = -1;
    }
  }
  __syncthreads();
  for (int k = tid; k < NBF + NBR_; k += 256) {
    int c = hist[k];
    gpos[k] = c ? atomicAdd(&bcur[bb + k], c) : 0;
  }
  __syncthreads();
#pragma unroll
  for (int j = 0; j < 16; j++) {
    if (dv[j] >= 0) {
      int s1 = atomicAdd(&gpos[dv[j] >> SHF], 1);
      stage[s1] = ((dv[j] & ((1 << SHF) - 1)) << 17) | sv[j];
      int s2 = atomicAdd(&gpos[NBF + (sv[j] >> SHR)], 1);
      stage[s2] = ((sv[j] & ((1 << SHR) - 1)) << 17) | dv[j];
    }
  }
}

__global__ void scan_counts(const int* __restrict__ bcur, int* __restrict__ bstart,
                            int* __restrict__ off_sentinel) {
  __shared__ int buf[256];
  int t = threadIdx.x;
  int base = 0;
  for (int c0 = 0; c0 < NBTOT; c0 += 256) {
    int id = c0 + t;
    int v = (id < NBTOT) ? (bcur[id] - pstart(id)) : 0;
    buf[t] = v; __syncthreads();
    for (int o = 1; o < 256; o <<= 1) {
      int a = (t >= o) ? buf[t - o] : 0;
      __syncthreads();
      buf[t] += a;
      __syncthreads();
    }
    if (id < NBTOT) bstart[id] = buf[t] - v + base;
    base += buf[255];
    __syncthreads();
  }
  if (t == 0) { bstart[NBTOT] = base; *off_sentinel = base; }
}

// Phase B: one block per bucket, packed-int staging.
// s/r-target buckets: composite (target x payload-region) counting sort so each
// adjacency list is sorted by source region -> co-resident sr waves sweep xm in
// lockstep -> L2-resident gather window.
__global__ __launch_bounds__(256) void scatter_bucket(
    const int* __restrict__ stage, const int* __restrict__ bstart,
    int* __restrict__ cur, int* __restrict__ off, int* __restrict__ pool) {
  __shared__ int win[WCAP];
  __shared__ int hist[NKEY];  // >= MAXNODES
  __shared__ int part[256];
  int b = blockIdx.x;
  BInfo bi = binfo(b);
  int p0 = pstart(b);
  int d0 = bstart[b];
  int sz = bstart[b + 1] - d0;
  int nn = bi.ne - bi.ns;
  int t = threadIdx.x;
  bool srb = (b >= 196 && b < 509) || (b >= 705 && b < 830);

  if (srb) {
    for (int k = t; k < NKEY; k += 256) hist[k] = 0;
    __syncthreads();
    for (int k = t; k < sz; k += 256) {
      unsigned e = (unsigned)stage[p0 + k];
      atomicAdd(&hist[(e >> 17) * NREG + ((e & 0x1FFFF) >> 11)], 1);
    }
    __syncthreads();
    int c4[4]; int sum4 = 0;
#pragma unroll
    for (int i = 0; i < 4; i++) {
      int idx = 4 * t + i;
      c4[i] = (idx < NKEY) ? hist[idx] : 0;
      sum4 += c4[i];
    }
    part[t] = sum4;
    __syncthreads();
    for (int o = 1; o < 256; o <<= 1) {
      int a = (t >= o) ? part[t - o] : 0;
      __syncthreads();
      part[t] += a;
      __syncthreads();
    }
    int run = part[t] - sum4;
#pragma unroll
    for (int i = 0; i < 4; i++) {
      int idx = 4 * t + i;
      if (idx < NKEY) { hist[idx] = run; run += c4[i]; }
    }
    __syncthreads();
    if (t < nn) off[bi.g + bi.ns + t] = d0 + hist[t * NREG];
    __syncthreads();
    for (int k = t; k < sz; k += 256) {
      unsigned e = (unsigned)stage[p0 + k];
      int slot = atomicAdd(&hist[(e >> 17) * NREG + ((e & 0x1FFFF) >> 11)], 1);
      win[slot] = e & 0x1FFFF;
    }
    __syncthreads();
    for (int k = t; k < sz; k += 256) pool[d0 + k] = win[k];
    return;
  }

  for (int k = t; k < nn; k += 256) hist[k] = 0;
  __syncthreads();
  for (int k = t; k < sz; k += 256)
    atomicAdd(&hist[((unsigned)stage[p0 + k]) >> 17], 1);
  __syncthreads();
  int a0 = (2 * t < nn) ? hist[2 * t] : 0;
  int a1 = (2 * t + 1 < nn) ? hist[2 * t + 1] : 0;
  part[t] = a0 + a1;
  __syncthreads();
  for (int o = 1; o < 256; o <<= 1) {
    int a = (t >= o) ? part[t - o] : 0;
    __syncthreads();
    part[t] += a;
    __syncthreads();
  }
  int e0 = part[t] - a0 - a1;
  int e1 = e0 + a0;
  if (2 * t < nn)     { off[bi.g + bi.ns + 2 * t] = d0 + e0; hist[2 * t] = e0; }
  if (2 * t + 1 < nn) { off[bi.g + bi.ns + 2 * t + 1] = d0 + e1; hist[2 * t + 1] = e1; }
  __syncthreads();
  if (sz <= WCAP) {
    for (int k = t; k < sz; k += 256) {
      int e = stage[p0 + k];
      int slot = atomicAdd(&hist[((unsigned)e) >> 17], 1);
      win[slot] = e & 0x1FFFF;
    }
    __syncthreads();
    for (int k = t; k < sz; k += 256) pool[d0 + k] = win[k];
  } else {
    // fallback (never expected statistically; correctness-only path)
    for (int k = t; k < sz; k += 256) {
      int e = stage[p0 + k];
      int local = ((unsigned)e) >> 17;
      int slot = atomicAdd(&cur[bi.g + bi.ns + local], 1);
      pool[d0 + hist[local] + slot] = e & 0x1FFFF;
    }
  }
}

// merged prep: weight transpose+cast, dinv, fused bias (one launch)
// bf16 transposed weights wt[(l*9+slot)][n][k], slots:
// 0..3 = sage_Wl rel0..3; 4,5 = gcn_W; 6 = Wr0+Wr2; 7 = Wr1; 8 = Wr3
__global__ void prep_all(const float* __restrict__ sWl, const float* __restrict__ sWr,
                         const float* __restrict__ gW, const float* __restrict__ sbl,
                         const float* __restrict__ gb,
                         const int* __restrict__ off1, const int* __restrict__ off2,
                         float* __restrict__ dinv1, float* __restrict__ dinv2,
                         unsigned short* __restrict__ wt, float* __restrict__ biasM) {
  int i = blockIdx.x * blockDim.x + threadIdx.x;
  if (i < 18 * 16384) {
    int mat = i >> 14, l = mat / 9, slot = mat % 9;
    int idx = i & 16383, nn = idx >> 7, kk = idx & 127;
    int s_ = kk * 128 + nn;  // source [k][n] row-major
    float v;
    if (slot < 4)      v = sWl[((l * 4 + slot) << 14) + s_];
    else if (slot < 6) v = gW[((l * 2 + (slot - 4)) << 14) + s_];
    else if (slot == 6) v = sWr[((l * 4 + 0) << 14) + s_] + sWr[((l * 4 + 2) << 14) + s_];
    else if (slot == 7) v = sWr[((l * 4 + 1) << 14) + s_];
    else                v = sWr[((l * 4 + 3) << 14) + s_];
    wt[i] = f2bf(v);
  }
  if (i < NMN) {
    dinv1[i] = rsqrtf((float)(off1[i + 1] - off1[i] + 1));
    dinv2[i] = rsqrtf((float)(off2[i + 1] - off2[i] + 1));
  }
  if (i < 256) {
    int l = i >> 7, j = i & 127;
    biasM[i] = sbl[(l * 4 + 0) * 128 + j] + sbl[(l * 4 + 2) * 128 + j] +
               gb[(l * 2 + 0) * 128 + j] + gb[(l * 2 + 1) * 128 + j];
  }
}

__global__ void cast_all(const float2* __restrict__ es, const float2* __restrict__ em,
                         const float2* __restrict__ er, unsigned* __restrict__ os,
                         unsigned* __restrict__ om, unsigned* __restrict__ orr) {
  int i = blockIdx.x * blockDim.x + threadIdx.x;
  if (i < NSN * 64) { float2 v = es[i]; os[i] = pack2(v.x, v.y); }
  if (i < NMN * 64) { float2 v = em[i]; om[i] = pack2(v.x, v.y); }
  if (i < NRN * 64) { float2 v = er[i]; orr[i] = pack2(v.x, v.y); }
}

// ---------------- fused layer aggregation (1 wave per node) ------------------

template <bool GCN>
__device__ __forceinline__ f32x2 agg_list(const char* __restrict__ xb,
                                          const int* __restrict__ pool,
                                          const float* __restrict__ dinv,
                                          int s, int e, int l4) {
  f32x2 a0 = (f32x2)(0.f), a1 = (f32x2)(0.f);
  if (e <= s) return a0;
  for (int i0 = s; i0 < e; i0 += 64) {
    int cnt = min(64, e - i0);
    int pidx = min(i0 + (l4 >> 2), e - 1);
    int pv = pool[pidx];                       // coalesced: 64 consecutive ints
    float dvv = 0.f;
    if (GCN) dvv = dinv[pv];                   // per-lane 4B gather, 1/64 edges
    int k = 0;
    for (; k + 16 <= cnt; k += 16) {
      unsigned vv[16];
      float sc[16];
#pragma unroll
      for (int j = 0; j < 16; j++) {
        int u = __builtin_amdgcn_readlane(pv, k + j);       // SGPR node id
        if (GCN) sc[j] = rl_f(dvv, k + j);
        vv[j] = *(const unsigned*)(xb + (((unsigned)u << 8) + (unsigned)l4));
      }
#pragma unroll
      for (int j = 0; j < 16; j++) {
        float m = GCN ? sc[j] : 1.0f;
        if (j & 1) {
          a1.x = fmaf(bf_lo(vv[j]), m, a1.x);
          a1.y = fmaf(bf_hi(vv[j]), m, a1.y);
        } else {
          a0.x = fmaf(bf_lo(vv[j]), m, a0.x);
          a0.y = fmaf(bf_hi(vv[j]), m, a0.y);
        }
      }
    }
    if (k < cnt) {  // masked chunk (uniform predicates -> scalar selects)
      unsigned vv[16];
      float sc[16];
#pragma unroll
      for (int j = 0; j < 16; j++) {
        int kk = min(k + j, cnt - 1);
        int u = __builtin_amdgcn_readlane(pv, kk);
        float m;
        if (k + j < cnt)
          m = GCN ? rl_f(dvv, kk) : 1.0f;
        else
          m = 0.0f;
        sc[j] = m;
        vv[j] = *(const unsigned*)(xb + (((unsigned)u << 8) + (unsigned)l4));
      }
#pragma unroll
      for (int j = 0; j < 16; j++) {
        if (j & 1) {
          a1.x = fmaf(bf_lo(vv[j]), sc[j], a1.x);
          a1.y = fmaf(bf_hi(vv[j]), sc[j], a1.y);
        } else {
          a0.x = fmaf(bf_lo(vv[j]), sc[j], a0.x);
          a0.y = fmaf(bf_hi(vv[j]), sc[j], a0.y);
        }
      }
    }
  }
  return a0 + a1;
}

__global__ __launch_bounds__(256) void agg_all(
    const unsigned* __restrict__ xs, const unsigned* __restrict__ xm,
    const unsigned* __restrict__ xr, const int* __restrict__ pool,
    const int* __restrict__ off_sm, const int* __restrict__ off_rm,
    const int* __restrict__ off_si, const int* __restrict__ off_si2,
    const int* __restrict__ off_ms, const int* __restrict__ off_mr,
    const float* __restrict__ dinv1, const float* __restrict__ dinv2,
    unsigned* __restrict__ aggA, unsigned* __restrict__ aggB,
    unsigned* __restrict__ aggC, unsigned* __restrict__ aggD,
    unsigned* __restrict__ aggS, unsigned* __restrict__ aggR) {
  int wv = blockIdx.x * 4 + (threadIdx.x >> 6);
  wv = __builtin_amdgcn_readfirstlane(wv);
  int l = threadIdx.x & 63;
  int l4 = l << 2;

  if (wv < SR_TOTAL) {
    // s/r nodes: plain mean over m-neighbors (long region-sorted lists,
    // co-resident cohort sweeps xm regions in lockstep)
    int node;
    const int* offp;
    unsigned* outb;
    if (wv < NSN) { node = wv; offp = off_ms; outb = aggS; }
    else          { node = wv - NSN; offp = off_mr; outb = aggR; }
    int s = offp[node], e = offp[node + 1];
    f32x2 a = agg_list<false>((const char*)xm, pool, nullptr, s, e, l4);
    float inv = (e > s) ? 1.0f / (float)(e - s) : 0.0f;
    outb[(size_t)node * 64 + l] = pack2(a.x * inv, a.y * inv);
  } else {
    int w = wv - SR_TOTAL;
    // hoist all offset pairs + self feature (independent s_loads up front)
    int sA = off_sm[w],  eA = off_sm[w + 1];
    int sB = off_rm[w],  eB = off_rm[w + 1];
    int sC = off_si[w],  eC = off_si[w + 1];
    int sD = off_si2[w], eD = off_si2[w + 1];
    unsigned xv = xm[(size_t)w * 64 + l];
    float dw1 = dinv1[w], dw2_ = dinv2[w];

    {
      f32x2 a = agg_list<false>((const char*)xs, pool, nullptr, sA, eA, l4);
      float inv = (eA > sA) ? 1.0f / (float)(eA - sA) : 0.0f;
      aggA[(size_t)w * 64 + l] = pack2(a.x * inv, a.y * inv);
    }
    {
      f32x2 a = agg_list<false>((const char*)xr, pool, nullptr, sB, eB, l4);
      float inv = (eB > sB) ? 1.0f / (float)(eB - sB) : 0.0f;
      aggB[(size_t)w * 64 + l] = pack2(a.x * inv, a.y * inv);
    }
    {
      f32x2 a = agg_list<true>((const char*)xm, pool, dinv1, sC, eC, l4);
      float dsq = dw1 * dw1;
      float rx = a.x * dw1 + bf_lo(xv) * dsq;
      float ry = a.y * dw1 + bf_hi(xv) * dsq;
      aggC[(size_t)w * 64 + l] = pack2(rx, ry);
    }
    {
      f32x2 a = agg_list<true>((const char*)xm, pool, dinv2, sD, eD, l4);
      float dsq = dw2_ * dw2_;
      float rx = a.x * dw2_ + bf_lo(xv) * dsq;
      float ry = a.y * dw2_ + bf_hi(xv) * dsq;
      aggD[(size_t)w * 64 + l] = pack2(rx, ry);
    }
  }
}

// ---------------- MFMA GEMM: out = relu(bias + sum_p A_p @ W_p) ----------------
// single dispatch covers m (5 terms), s (2 terms), r (2 terms) tiles

#define LDA 136
#define NBS 79    // ceil(5000/64)
#define NBR 32    // ceil(2000/64)
#define NBM 1563  // ceil(100000/64)
#define NB_GEMM (NBM + NBS + NBR)  // 1674

__global__ __launch_bounds__(256) void gemm_all(
    const unsigned short* __restrict__ aggA, const unsigned short* __restrict__ aggB,
    const unsigned short* __restrict__ aggC, const unsigned short* __restrict__ aggD,
    const unsigned short* __restrict__ xm_c, const unsigned short* __restrict__ aggS,
    const unsigned short* __restrict__ xs_c, const unsigned short* __restrict__ aggR,
    const unsigned short* __restrict__ xr_c,
    const unsigned short* __restrict__ wt, int layer,
    const float* __restrict__ biasM, const float* __restrict__ sbl,
    unsigned short* __restrict__ xm_n, unsigned short* __restrict__ xs_n,
    unsigned short* __restrict__ xr_n) {
  __shared__ __align__(16) unsigned short As[64 * LDA];
  __shared__ __align__(16) unsigned short Ws[128 * LDA];

  int b = blockIdx.x, tid = threadIdx.x;
  int w = tid >> 6, lane = tid & 63;
  int q = lane >> 4, c = lane & 15;

  const unsigned short* wbase = wt + (((size_t)layer * 9) << 14);
  const unsigned short* Ap[5];
  const unsigned short* Wp[5];
  int base, n;
  unsigned short* outp;
  const float* bias;

  if (b < NBM) {
    base = b * 64; n = NMN; outp = xm_n; bias = biasM + layer * 128;
    Ap[0] = aggA; Wp[0] = wbase + (0 << 14);
    Ap[1] = aggB; Wp[1] = wbase + (2 << 14);
    Ap[2] = aggC; Wp[2] = wbase + (4 << 14);
    Ap[3] = aggD; Wp[3] = wbase + (5 << 14);
    Ap[4] = xm_c; Wp[4] = wbase + (6 << 14);
  } else if (b < NBM + NBS) {
    base = (b - NBM) * 64; n = NSN; outp = xs_n; bias = sbl + (layer * 4 + 1) * 128;
    Ap[0] = aggS; Wp[0] = wbase + (1 << 14);
    Ap[1] = xs_c; Wp[1] = wbase + (7 << 14);
    Ap[2] = nullptr; Ap[3] = nullptr; Ap[4] = nullptr;
    Wp[2] = nullptr; Wp[3] = nullptr; Wp[4] = nullptr;
  } else {
    base = (b - NBM - NBS) * 64; n = NRN; outp = xr_n; bias = sbl + (layer * 4 + 3) * 128;
    Ap[0] = aggR; Wp[0] = wbase + (3 << 14);
    Ap[1] = xr_c; Wp[1] = wbase + (8 << 14);
    Ap[2] = nullptr; Ap[3] = nullptr; Ap[4] = nullptr;
    Wp[2] = nullptr; Wp[3] = nullptr; Wp[4] = nullptr;
  }

  float bias_v[8];
#pragma unroll
  for (int n0 = 0; n0 < 8; n0++) bias_v[n0] = bias[n0 * 16 + c];

  f32x4 acc[8];
#pragma unroll
  for (int n0 = 0; n0 < 8; n0++) acc[n0] = (f32x4){0.f, 0.f, 0.f, 0.f};

  for (int p = 0; p < 5; p++) {
    if (!Ap[p]) continue;
    __syncthreads();
    for (int j = tid; j < 2048; j += 256) {
      int row = j >> 4, colc = (j & 15) * 8;
      *(uint4*)&Ws[row * LDA + colc] = *(const uint4*)(Wp[p] + row * 128 + colc);
    }
    for (int j = tid; j < 1024; j += 256) {
      int row = j >> 4, colc = (j & 15) * 8;
      uint4 v = make_uint4(0u, 0u, 0u, 0u);
      if (base + row < n) v = *(const uint4*)(Ap[p] + (size_t)(base + row) * 128 + colc);
      *(uint4*)&As[row * LDA + colc] = v;
    }
    __syncthreads();

    int arow = (w * 16 + c) * LDA;
#pragma unroll
    for (int k0 = 0; k0 < 128; k0 += 32) {
      bf16x8 af = *(const bf16x8*)&As[arow + k0 + q * 8];
#pragma unroll
      for (int n0 = 0; n0 < 8; n0++) {
        bf16x8 bfv = *(const bf16x8*)&Ws[(n0 * 16 + c) * LDA + k0 + q * 8];
        acc[n0] = __builtin_amdgcn_mfma_f32_16x16x32_bf16(af, bfv, acc[n0], 0, 0, 0);
      }
    }
  }

  __syncthreads();
#pragma unroll
  for (int n0 = 0; n0 < 8; n0++) {
#pragma unroll
    for (int reg = 0; reg < 4; reg++) {
      float v = acc[n0][reg] + bias_v[n0];
      v = fmaxf(v, 0.f);
      As[(w * 16 + q * 4 + reg) * LDA + n0 * 16 + c] = f2bf(v);
    }
  }
  __syncthreads();
  for (int j = tid; j < 1024; j += 256) {
    int row = j >> 4, colc = (j & 15) * 8;
    if (base + row < n)
      *(uint4*)(outp + (size_t)(base + row) * 128 + colc) = *(const uint4*)&As[row * LDA + colc];
  }
}

// ---------------- final dot products (4 pairs per wave) ----------------

__global__ void dots_kernel(const unsigned* __restrict__ xs, const unsigned* __restrict__ xm,
                            const unsigned* __restrict__ xr, const int* __restrict__ ls,
                            const int* __restrict__ lm, const int* __restrict__ lr,
                            float* __restrict__ out) {
  int wv = (blockIdx.x * blockDim.x + threadIdx.x) >> 6;
  int lane = threadIdx.x & 63;
  int q = lane >> 4, h = lane & 15;
  int i = wv * 4 + q;
  if (i >= LBL) return;
  int im = lm[i], is = ls[i], ir = lr[i];
  uint4 mv = *(const uint4*)(xm + (size_t)im * 64 + h * 4);
  uint4 sv = *(const uint4*)(xs + (size_t)is * 64 + h * 4);
  uint4 rv = *(const uint4*)(xr + (size_t)ir * 64 + h * 4);
  float fm[8], fs[8], fr[8];
  unpack8(mv, fm); unpack8(sv, fs); unpack8(rv, fr);
  float p1 = 0.f, p2 = 0.f;
#pragma unroll
  for (int j = 0; j < 8; j++) { p1 = fmaf(fs[j], fm[j], p1); p2 = fmaf(fr[j], fm[j], p2); }
#pragma unroll
  for (int m = 1; m < 16; m <<= 1) {
    p1 += __shfl_xor(p1, m, 64);
    p2 += __shfl_xor(p2, m, 64);
  }
  if (h == 0) { out[i] = p1; out[LBL + i] = p2; }
}

// ---------------- host launcher ----------------

extern "C" void kernel_launch(void* const* d_in, const int* in_sizes, int n_in,
                              void* d_out, int out_size, void* d_ws, size_t ws_size,
                              hipStream_t stream) {
  const float* emb_s = (const float*)d_in[0];
  const float* emb_m = (const float*)d_in[1];
  const float* emb_r = (const float*)d_in[2];
  const float* sWl = (const float*)d_in[3];
  const float* sbl = (const float*)d_in[4];
  const float* sWr = (const float*)d_in[5];
  const float* gW  = (const float*)d_in[6];
  const float* gb  = (const float*)d_in[7];
  const int* src_sm  = (const int*)d_in[8];
  const int* dst_sm  = (const int*)d_in[9];
  const int* src_rm  = (const int*)d_in[10];
  const int* dst_rm  = (const int*)d_in[11];
  const int* src_sim = (const int*)d_in[12];
  const int* dst_sim = (const int*)d_in[13];
  const int* lbl_s = (const int*)d_in[14];
  const int* lbl_m = (const int*)d_in[15];
  const int* lbl_r = (const int*)d_in[16];
  float* out = (float*)d_out;

  char* p = (char*)d_ws;
  auto alloc = [&](size_t bytes) -> char* {
    char* r = p;
    p += (bytes + 255) & ~(size_t)255;
    return r;
  };

  int* cnt_base = (int*)alloc(sizeof(int) * CNT_TOTAL);  // fallback cursors only

  int* off_base = (int*)alloc(sizeof(int) * (CNT_TOTAL + 1));
  int* off_sm  = off_base;
  int* off_ms  = off_sm + NMN;
  int* off_rm  = off_ms + NSN;
  int* off_mr  = off_rm + NMN;
  int* off_si  = off_mr + NRN;
  int* off_si2 = off_si + NMN;

  int* bstart = (int*)alloc(sizeof(int) * 1280);
  int* bcur   = (int*)alloc(sizeof(int) * 1280);
  int* pool = (int*)alloc(sizeof(int) * POOL_TOTAL);

  float* dinv1 = (float*)alloc(sizeof(float) * NMN);
  float* dinv2 = (float*)alloc(sizeof(float) * NMN);

  unsigned* xsb = (unsigned*)alloc(sizeof(unsigned) * (size_t)NSN * 64);
  unsigned* xmb = (unsigned*)alloc(sizeof(unsigned) * (size_t)NMN * 64);
  unsigned* xrb = (unsigned*)alloc(sizeof(unsigned) * (size_t)NRN * 64);
  unsigned* xs0 = (unsigned*)alloc(sizeof(unsigned) * (size_t)NSN * 64);
  unsigned* xs1 = (unsigned*)alloc(sizeof(unsigned) * (size_t)NSN * 64);
  unsigned* xm0 = (unsigned*)alloc(sizeof(unsigned) * (size_t)NMN * 64);
  unsigned* xm1 = (unsigned*)alloc(sizeof(unsigned) * (size_t)NMN * 64);
  unsigned* xr0 = (unsigned*)alloc(sizeof(unsigned) * (size_t)NRN * 64);
  unsigned* xr1 = (unsigned*)alloc(sizeof(unsigned) * (size_t)NRN * 64);
  unsigned* aggA = (unsigned*)alloc(sizeof(unsigned) * (size_t)NMN * 64);
  unsigned* aggB = (unsigned*)alloc(sizeof(unsigned) * (size_t)NMN * 64);
  unsigned* aggC = (unsigned*)alloc(sizeof(unsigned) * (size_t)NMN * 64);
  unsigned* aggD = (unsigned*)alloc(sizeof(unsigned) * (size_t)NMN * 64);
  unsigned* aggS = (unsigned*)alloc(sizeof(unsigned) * (size_t)NSN * 64);
  unsigned* aggR = (unsigned*)alloc(sizeof(unsigned) * (size_t)NRN * 64);

  unsigned short* wt = (unsigned short*)alloc(sizeof(unsigned short) * 18 * 16384);
  float* biasM = (float*)alloc(sizeof(float) * 2 * 128);

  // packed staging aliases aggA/aggB (49.4 MB <= 51.2 MB contiguous); staging
  // is fully consumed by scatter_bucket before agg_all writes aggA/aggB
  // (stream-ordered).
  int* stage = (int*)aggA;

  // ---- CSR build: padded multisplit (packed int) -> count scan -> scatter ----
  init_all<<<(CNT_TOTAL + 255) / 256, 256, 0, stream>>>(bcur, cnt_base);
  multisplit<9, 196, 4, 313><<<(ESM + 4095) / 4096, 256, 0, stream>>>(
      src_sm, dst_sm, ESM, bcur, 0, stage);
  multisplit<9, 196, 4, 125><<<(ERM + 4095) / 4096, 256, 0, stream>>>(
      src_rm, dst_rm, ERM, bcur, 509, stage);
  multisplit<9, 196, 9, 196><<<(ESIM + 4095) / 4096, 256, 0, stream>>>(
      src_sim, dst_sim, ESIM, bcur, 830, stage);
  scan_counts<<<1, 256, 0, stream>>>(bcur, bstart, off_base + CNT_TOTAL);
  scatter_bucket<<<NBTOT, 256, 0, stream>>>(stage, bstart, cnt_base, off_base, pool);

  prep_all<<<(18 * 16384 + 255) / 256, 256, 0, stream>>>(
      sWl, sWr, gW, sbl, gb, off_si, off_si2, dinv1, dinv2, wt, biasM);
  cast_all<<<(NMN * 64 + 255) / 256, 256, 0, stream>>>((const float2*)emb_s, (const float2*)emb_m,
                                                       (const float2*)emb_r, xsb, xmb, xrb);

  const int AGG_GRID = (SR_TOTAL + NMN) / 4;  // 26750 blocks, 1 wave per node, sr first
  for (int l = 0; l < 2; ++l) {
    const unsigned* xs_c = l ? xs0 : xsb;
    const unsigned* xm_c = l ? xm0 : xmb;
    const unsigned* xr_c = l ? xr0 : xrb;
    unsigned* xs_n = l ? xs1 : xs0;
    unsigned* xm_n = l ? xm1 : xm0;
    unsigned* xr_n = l ? xr1 : xr0;

    agg_all<<<AGG_GRID, 256, 0, stream>>>(
        xs_c, xm_c, xr_c, pool, off_sm, off_rm, off_si, off_si2, off_ms, off_mr,
        dinv1, dinv2, aggA, aggB, aggC, aggD, aggS, aggR);

    gemm_all<<<NB_GEMM, 256, 0, stream>>>(
        (const unsigned short*)aggA, (const unsigned short*)aggB,
        (const unsigned short*)aggC, (const unsigned short*)aggD,
        (const unsigned short*)xm_c, (const unsigned short*)aggS,
        (const unsigned short*)xs_c, (const unsigned short*)aggR,
        (const unsigned short*)xr_c, wt, l, biasM, sbl,
        (unsigned short*)xm_n, (unsigned short*)xs_n, (unsigned short*)xr_n);
  }

  dots_kernel<<<(LBL * 16 + 255) / 256, 256, 0, stream>>>(xs1, xm1, xr1, lbl_s, lbl_m, lbl_r, out);
}